// Round 1
// baseline (31150.156 us; speedup 1.0000x reference)
//
#include <hip/hip_runtime.h>
#include <math.h>

#define L_  12
#define B_  2
#define T_  448
#define D_  768
#define H_  12
#define HD_ 64
#define V_  51865
#define NC_ 448
#define CT_ 1500
#define FF_ 3072
#define M_  (B_*T_)   // 896 rows

// ---------------- embedding ----------------
__global__ void embed_k(const int* __restrict__ tokens, const float* __restrict__ tok_emb,
                        const float* __restrict__ pos_emb, float* __restrict__ x) {
    int idx = blockIdx.x * 256 + threadIdx.x;
    if (idx >= M_ * D_) return;
    int row = idx / D_, d = idx % D_;
    int t = row % T_;
    int tok = tokens[row];
    x[idx] = tok_emb[(size_t)tok * D_ + d] + pos_emb[(size_t)t * D_ + d];
}

// ---------------- layernorm (block per row, 256 thr) ----------------
__global__ __launch_bounds__(256) void ln_k(const float* __restrict__ x, const float* __restrict__ g,
                                            const float* __restrict__ b, float* __restrict__ out) {
    int row = blockIdx.x;
    const float* xr = x + (size_t)row * D_;
    float s = 0.f, ss = 0.f;
    for (int i = threadIdx.x; i < D_; i += 256) { float v = xr[i]; s += v; ss += v * v; }
    for (int o = 32; o > 0; o >>= 1) { s += __shfl_down(s, o); ss += __shfl_down(ss, o); }
    __shared__ float red0[4], red1[4];
    __shared__ float bm, binv;
    int wid = threadIdx.x >> 6, lid = threadIdx.x & 63;
    if (lid == 0) { red0[wid] = s; red1[wid] = ss; }
    __syncthreads();
    if (threadIdx.x == 0) {
        float S = 0.f, SS = 0.f;
        for (int i = 0; i < 4; i++) { S += red0[i]; SS += red1[i]; }
        float m = S / D_;
        float var = SS / D_ - m * m;
        bm = m; binv = rsqrtf(var + 1e-5f);
    }
    __syncthreads();
    float m = bm, inv = binv;
    float* orow = out + (size_t)row * D_;
    for (int i = threadIdx.x; i < D_; i += 256)
        orow[i] = (xr[i] - m) * inv * g[i] + b[i];
}

// ---------------- generic tiled fp32 GEMM: C = A(MxK) @ B(KxN) [+bias] [+resid] ----------------
#define BLK 64
#define KT  16
__global__ __launch_bounds__(256) void gemm_nn_k(const float* __restrict__ A, const float* __restrict__ Bm,
                                                 const float* __restrict__ bias, const float* __restrict__ resid,
                                                 float* __restrict__ C, int M, int N, int K) {
    __shared__ float As[KT][BLK + 1];
    __shared__ float Bs[KT][BLK + 1];
    int tid = threadIdx.x;
    int tx = tid & 15, ty = tid >> 4;
    int m0 = blockIdx.y * BLK, n0 = blockIdx.x * BLK;
    float acc[4][4] = {};
    for (int kt = 0; kt < K; kt += KT) {
        for (int i = tid; i < BLK * KT; i += 256) {
            int m = i >> 4, kk = i & 15;
            int gm = m0 + m;
            As[kk][m] = (gm < M) ? A[(size_t)gm * K + kt + kk] : 0.f;
        }
        for (int i = tid; i < KT * BLK; i += 256) {
            int kk = i >> 6, n = i & 63;
            int gn = n0 + n;
            Bs[kk][n] = (gn < N) ? Bm[(size_t)(kt + kk) * N + gn] : 0.f;
        }
        __syncthreads();
        #pragma unroll
        for (int kk = 0; kk < KT; kk++) {
            float a[4], bb[4];
            #pragma unroll
            for (int i = 0; i < 4; i++) a[i] = As[kk][ty * 4 + i];
            #pragma unroll
            for (int j = 0; j < 4; j++) bb[j] = Bs[kk][tx * 4 + j];
            #pragma unroll
            for (int i = 0; i < 4; i++)
                #pragma unroll
                for (int j = 0; j < 4; j++) acc[i][j] += a[i] * bb[j];
        }
        __syncthreads();
    }
    #pragma unroll
    for (int i = 0; i < 4; i++) {
        int gm = m0 + ty * 4 + i;
        if (gm >= M) continue;
        #pragma unroll
        for (int j = 0; j < 4; j++) {
            int gn = n0 + tx * 4 + j;
            if (gn >= N) continue;
            float v = acc[i][j];
            if (bias)  v += bias[gn];
            if (resid) v += resid[(size_t)gm * N + gn];
            C[(size_t)gm * N + gn] = v;
        }
    }
}

// ---------------- NT GEMM: C = A(MxK) @ Bt(NxK)^T  (logits vs embedding) ----------------
__global__ __launch_bounds__(256) void gemm_nt_k(const float* __restrict__ A, const float* __restrict__ Bt,
                                                 float* __restrict__ C, int M, int N, int K) {
    __shared__ float As[KT][BLK + 1];
    __shared__ float Bs[KT][BLK + 1];
    int tid = threadIdx.x;
    int tx = tid & 15, ty = tid >> 4;
    int m0 = blockIdx.y * BLK, n0 = blockIdx.x * BLK;
    float acc[4][4] = {};
    for (int kt = 0; kt < K; kt += KT) {
        for (int i = tid; i < BLK * KT; i += 256) {
            int m = i >> 4, kk = i & 15;
            int gm = m0 + m;
            As[kk][m] = (gm < M) ? A[(size_t)gm * K + kt + kk] : 0.f;
        }
        for (int i = tid; i < BLK * KT; i += 256) {
            int n = i >> 4, kk = i & 15;
            int gn = n0 + n;
            Bs[kk][n] = (gn < N) ? Bt[(size_t)gn * K + kt + kk] : 0.f;
        }
        __syncthreads();
        #pragma unroll
        for (int kk = 0; kk < KT; kk++) {
            float a[4], bb[4];
            #pragma unroll
            for (int i = 0; i < 4; i++) a[i] = As[kk][ty * 4 + i];
            #pragma unroll
            for (int j = 0; j < 4; j++) bb[j] = Bs[kk][tx * 4 + j];
            #pragma unroll
            for (int i = 0; i < 4; i++)
                #pragma unroll
                for (int j = 0; j < 4; j++) acc[i][j] += a[i] * bb[j];
        }
        __syncthreads();
    }
    #pragma unroll
    for (int i = 0; i < 4; i++) {
        int gm = m0 + ty * 4 + i;
        if (gm >= M) continue;
        #pragma unroll
        for (int j = 0; j < 4; j++) {
            int gn = n0 + tx * 4 + j;
            if (gn >= N) continue;
            C[(size_t)gm * N + gn] = acc[i][j];
        }
    }
}

// ---------------- attention scores: S[bh,i,j] = 0.125 * q_h(i)·k_h(j)  (+causal mask) ----------------
__global__ __launch_bounds__(256) void attn_scores_k(const float* __restrict__ q, const float* __restrict__ k,
                                                     float* __restrict__ S, int Tq, int Tk, int causal) {
    int bh = blockIdx.z;
    int b = bh / H_, h = bh % H_;
    int i0 = blockIdx.y * 16, j0 = blockIdx.x * 16;
    __shared__ float Qs[16][HD_ + 1], Ks[16][HD_ + 1];
    int tid = threadIdx.x;
    for (int idx = tid; idx < 16 * HD_; idx += 256) {
        int r = idx >> 6, d = idx & 63;
        int gi = i0 + r;
        Qs[r][d] = (gi < Tq) ? q[((size_t)(b * Tq + gi)) * D_ + h * HD_ + d] : 0.f;
        int gj = j0 + r;
        Ks[r][d] = (gj < Tk) ? k[((size_t)(b * Tk + gj)) * D_ + h * HD_ + d] : 0.f;
    }
    __syncthreads();
    int tx = tid & 15, ty = tid >> 4;
    int gi = i0 + ty, gj = j0 + tx;
    if (gi >= Tq || gj >= Tk) return;
    float acc = 0.f;
    #pragma unroll
    for (int d = 0; d < HD_; d++) acc += Qs[ty][d] * Ks[tx][d];
    float val = acc * 0.125f;   // hd^-0.25 applied to both q and k -> 64^-0.5
    if (causal && gj > gi) val = -INFINITY;
    S[((size_t)bh * Tq + gi) * Tk + gj] = val;
}

// ---------------- row softmax ----------------
__global__ __launch_bounds__(256) void softmax_k(float* __restrict__ S, int ncols) {
    size_t row = blockIdx.x;
    float* r = S + row * (size_t)ncols;
    float mx = -INFINITY;
    for (int i = threadIdx.x; i < ncols; i += 256) mx = fmaxf(mx, r[i]);
    for (int o = 32; o > 0; o >>= 1) mx = fmaxf(mx, __shfl_down(mx, o));
    __shared__ float red[4];
    __shared__ float bmax, bsum;
    int wid = threadIdx.x >> 6, lid = threadIdx.x & 63;
    if (lid == 0) red[wid] = mx;
    __syncthreads();
    if (threadIdx.x == 0) {
        float m = -INFINITY;
        for (int i = 0; i < 4; i++) m = fmaxf(m, red[i]);
        bmax = m;
    }
    __syncthreads();
    mx = bmax;
    float s = 0.f;
    for (int i = threadIdx.x; i < ncols; i += 256) { float e = __expf(r[i] - mx); r[i] = e; s += e; }
    for (int o = 32; o > 0; o >>= 1) s += __shfl_down(s, o);
    if (lid == 0) red[wid] = s;
    __syncthreads();
    if (threadIdx.x == 0) {
        float t = 0.f;
        for (int i = 0; i < 4; i++) t += red[i];
        bsum = t;
    }
    __syncthreads();
    float inv = 1.f / bsum;
    for (int i = threadIdx.x; i < ncols; i += 256) r[i] *= inv;
}

// ---------------- attn output: out[b,i,h,:] = sum_j S[bh,i,j] * v[b,j,h,:] ----------------
__global__ __launch_bounds__(256) void attn_av_k(const float* __restrict__ S, const float* __restrict__ v,
                                                 float* __restrict__ out, int Tq, int Tk) {
    int tid = threadIdx.x;
    int d = tid & 63, r = tid >> 6;      // 4 query rows per block
    int i = blockIdx.x * 4 + r;
    int bh = blockIdx.y;
    int b = bh / H_, h = bh % H_;
    if (i >= Tq) return;
    const float* srow = S + ((size_t)bh * Tq + i) * Tk;
    const float* vcol = v + (size_t)b * Tk * D_ + h * HD_ + d;
    float acc = 0.f;
    #pragma unroll 4
    for (int j = 0; j < Tk; j++) acc += srow[j] * vcol[(size_t)j * D_];
    out[((size_t)(b * Tq + i)) * D_ + h * HD_ + d] = acc;
}

// ---------------- exact gelu ----------------
__global__ void gelu_k(float* __restrict__ x, int n) {
    int i = blockIdx.x * 256 + threadIdx.x;
    if (i < n) { float v = x[i]; x[i] = 0.5f * v * (1.f + erff(v * 0.70710678118f)); }
}

extern "C" void kernel_launch(void* const* d_in, const int* in_sizes, int n_in,
                              void* d_out, int out_size, void* d_ws, size_t ws_size,
                              hipStream_t stream) {
    const int*   tokens     = (const int*)d_in[0];
    const float* cross_k    = (const float*)d_in[3];
    const float* cross_v    = (const float*)d_in[4];
    const float* tok_emb    = (const float*)d_in[6];
    const float* pos_emb    = (const float*)d_in[7];
    const float* attn_ln_g  = (const float*)d_in[9];
    const float* attn_ln_b  = (const float*)d_in[10];
    const float* Wq         = (const float*)d_in[11];
    const float* bq         = (const float*)d_in[12];
    const float* Wk         = (const float*)d_in[13];
    const float* Wv         = (const float*)d_in[14];
    const float* bv         = (const float*)d_in[15];
    const float* Wo         = (const float*)d_in[16];
    const float* bo         = (const float*)d_in[17];
    const float* xattn_ln_g = (const float*)d_in[18];
    const float* xattn_ln_b = (const float*)d_in[19];
    const float* xWq        = (const float*)d_in[20];
    const float* xbq        = (const float*)d_in[21];
    const float* xWo        = (const float*)d_in[22];
    const float* xbo        = (const float*)d_in[23];
    const float* mlp_ln_g   = (const float*)d_in[24];
    const float* mlp_ln_b   = (const float*)d_in[25];
    const float* W1         = (const float*)d_in[26];
    const float* b1         = (const float*)d_in[27];
    const float* W2         = (const float*)d_in[28];
    const float* b2         = (const float*)d_in[29];
    const float* ln_g       = (const float*)d_in[30];
    const float* ln_b       = (const float*)d_in[31];

    float* outp   = (float*)d_out;
    float* logits = outp;                                  // (B,T,V)
    float* kcache = outp + (size_t)B_ * T_ * V_;           // (L,B,NC,D) — fully overwritten (offset=0, NC==T)
    float* vcache = kcache + (size_t)L_ * B_ * NC_ * D_;   // (L,B,NC,D)

    float* ws     = (float*)d_ws;
    float* x      = ws;                       // (M, D)
    float* h      = x + (size_t)M_ * D_;      // (M, D)
    float* q      = h + (size_t)M_ * D_;      // (M, D)
    float* attn   = q + (size_t)M_ * D_;      // (M, D)
    float* mlp    = attn + (size_t)M_ * D_;   // (M, FF)
    float* scores = mlp + (size_t)M_ * FF_;   // (B*H, T, CT) max

    embed_k<<<(M_ * D_ + 255) / 256, 256, 0, stream>>>(tokens, tok_emb, pos_emb, x);

    dim3 gD(D_ / BLK, M_ / BLK);          // 768-col GEMMs
    dim3 gF(FF_ / BLK, M_ / BLK);         // 3072-col GEMM
    dim3 gsS(T_ / 16, T_ / 16, B_ * H_);  // self scores
    dim3 gsC((CT_ + 15) / 16, T_ / 16, B_ * H_);
    dim3 gav(T_ / 4, B_ * H_);

    for (int l = 0; l < L_; l++) {
        const size_t wofs = (size_t)l * D_ * D_;
        float* kl = kcache + (size_t)l * B_ * NC_ * D_;
        float* vl = vcache + (size_t)l * B_ * NC_ * D_;

        // ---- self attention ----
        ln_k<<<M_, 256, 0, stream>>>(x, attn_ln_g + l * D_, attn_ln_b + l * D_, h);
        gemm_nn_k<<<gD, 256, 0, stream>>>(h, Wq + wofs, bq + l * D_, nullptr, q,  M_, D_, D_);
        gemm_nn_k<<<gD, 256, 0, stream>>>(h, Wk + wofs, nullptr,     nullptr, kl, M_, D_, D_);
        gemm_nn_k<<<gD, 256, 0, stream>>>(h, Wv + wofs, bv + l * D_, nullptr, vl, M_, D_, D_);
        attn_scores_k<<<gsS, 256, 0, stream>>>(q, kl, scores, T_, T_, 1);
        softmax_k<<<B_ * H_ * T_, 256, 0, stream>>>(scores, T_);
        attn_av_k<<<gav, 256, 0, stream>>>(scores, vl, attn, T_, T_);
        gemm_nn_k<<<gD, 256, 0, stream>>>(attn, Wo + wofs, bo + l * D_, x, x, M_, D_, D_);

        // ---- cross attention ----
        ln_k<<<M_, 256, 0, stream>>>(x, xattn_ln_g + l * D_, xattn_ln_b + l * D_, h);
        gemm_nn_k<<<gD, 256, 0, stream>>>(h, xWq + wofs, xbq + l * D_, nullptr, q, M_, D_, D_);
        attn_scores_k<<<gsC, 256, 0, stream>>>(q, cross_k + (size_t)l * B_ * CT_ * D_, scores, T_, CT_, 0);
        softmax_k<<<B_ * H_ * T_, 256, 0, stream>>>(scores, CT_);
        attn_av_k<<<gav, 256, 0, stream>>>(scores, cross_v + (size_t)l * B_ * CT_ * D_, attn, T_, CT_);
        gemm_nn_k<<<gD, 256, 0, stream>>>(attn, xWo + wofs, xbo + l * D_, x, x, M_, D_, D_);

        // ---- mlp ----
        ln_k<<<M_, 256, 0, stream>>>(x, mlp_ln_g + l * D_, mlp_ln_b + l * D_, h);
        gemm_nn_k<<<gF, 256, 0, stream>>>(h, W1 + (size_t)l * D_ * FF_, b1 + l * FF_, nullptr, mlp, M_, FF_, D_);
        gelu_k<<<(M_ * FF_ + 255) / 256, 256, 0, stream>>>(mlp, M_ * FF_);
        gemm_nn_k<<<gD, 256, 0, stream>>>(mlp, W2 + (size_t)l * FF_ * D_, b2 + l * D_, x, x, M_, D_, FF_);
    }

    // ---- final LN + logits vs token_embedding^T ----
    ln_k<<<M_, 256, 0, stream>>>(x, ln_g, ln_b, h);
    dim3 gV((V_ + BLK - 1) / BLK, M_ / BLK);
    gemm_nt_k<<<gV, 256, 0, stream>>>(h, tok_emb, logits, M_, V_, D_);
}